// Round 8
// baseline (254.975 us; speedup 1.0000x reference)
//
#include <hip/hip_runtime.h>

typedef float  f32x4  __attribute__((ext_vector_type(4)));
typedef float  f32x2  __attribute__((ext_vector_type(2)));
typedef short  bf16x8 __attribute__((ext_vector_type(8)));

#define TWOLOG2E   2.8853900817779268f
#define NLOG2E    -1.4426950408889634f
#define NTWOLOG2E -2.8853900817779268f

__device__ __forceinline__ unsigned short f2b(float f) {      // fp32 -> bf16 RNE
    unsigned int u = __builtin_bit_cast(unsigned int, f);
    u += 0x7fffu + ((u >> 16) & 1u);
    return (unsigned short)(u >> 16);
}
__device__ __forceinline__ float b2f(unsigned short s) {
    unsigned int u = ((unsigned int)s) << 16;
    return __builtin_bit_cast(float, u);
}
__device__ __forceinline__ unsigned int pk2(float lo, float hi) {
#if __has_builtin(__builtin_amdgcn_cvt_pk_bf16_f32)
    typedef __bf16 bf16x2 __attribute__((ext_vector_type(2)));
    bf16x2 p = __builtin_amdgcn_cvt_pk_bf16_f32(lo, hi);
    return __builtin_bit_cast(unsigned int, p);
#else
    return (unsigned int)f2b(lo) | ((unsigned int)f2b(hi) << 16);
#endif
}
__device__ __forceinline__ float frcp(float x) { return __builtin_amdgcn_rcpf(x); }
__device__ __forceinline__ float fex2(float x) { return __builtin_amdgcn_exp2f(x); }

// R21: barrier-free monolith. R14-R20 established: VALUBusy*dur ~ 97us constant
// across every structure; ~42% idle is the wave-per-layer PIPELINE itself
// (fill/drain + barrier coupling), not convoy (R19), not false deps (R20),
// not LDS latency (R18). Since the R18 orientation's epilogue output IS the
// next GEMM's B-frag, one wave can chain layer 0->1->2->3 for its own 16 rows
// entirely in registers: zero barriers after x-staging, zero LDS h traffic,
// zero fill/drain, all waves independent. Work per SIMD unchanged (131072
// cells). Needs all-4-layer weights resident: ain 96 + arc 128 + w01 8
// (layer-0 input K=2 -> 1 u32/g) + cbq 128 + h 16 + cp 32 + acc 32 + temps
// ~= 470 regs -> 1 wave/SIMD (launch_bounds(256,1), 512 budget), grid 256 =
// 1 block/CU (R19 showed breadth-first dispatch handles this).
// Orientation (R18): gates^T = W·h^T, W=A-operand, h=B-operand;
// RowMap(g,w): unit=8*(w>>2)+2*(g&3)+(w&1), gate=2*(g>>2)+((w>>1)&1);
// lane(m,q) D = 4 gates x units 8q+2j(+1) of batch m; pk2 words = B-frag.
// Weights pre-scaled -log2e (-2log2e g-gate); bias rides in MFMA C (cbq).
// Per-unit epilogue (floor: 5 exp2 + 2 rcp, packed f32x2 over unit pairs):
//   p1=(1+ei)(1+eg); cn' = [cp*p1 - 2log2e(1-eg)(1+ef)] * rcp(p1*(1+ef))
//   (cp = -2log2e*c);  ec = exp2(cp);  h = (1-ec)*rcp((1+eo)(1+ec))
// Health: WRITE_SIZE ~64KB & VGPR 420-512 = ok; WRITE in MBs = spilled (R15).
__global__ __launch_bounds__(256, 1)
void lstm_mfma(const float* __restrict__ xg,  const float* __restrict__ Wih0,
               const float* __restrict__ Wih, const float* __restrict__ Whh,
               const float* __restrict__ bih, const float* __restrict__ bhh,
               const float* __restrict__ Wlin,const float* __restrict__ blin,
               float* __restrict__ out) {
    __shared__ unsigned int xb[64 * 64];    // [t][blockRow] 2xbf16

    const int tid  = threadIdx.x;
    const int wv   = __builtin_amdgcn_readfirstlane(tid >> 6);  // row-group, uniform
    const int lane = tid & 63;
    const int m    = lane & 15;    // batch index within wave's 16 rows
    const int q    = lane >> 4;    // quad: unit octet 8q..8q+7, k-chunk q*8..
    const int row0 = blockIdx.x * 64;

    // stage x -> LDS bf16 [t][row] (block-cooperative, the only barrier)
    for (int i = tid; i < 4096; i += 256) {
        int r = i >> 6, t = i & 63;
        float x0 = xg[(size_t)(row0 + r) * 192 + t];
        float x1 = xg[(size_t)(row0 + r) * 192 + 64 + t];
        xb[t * 64 + r] = pk2(x0, x1);
    }

    // ---- one-time gather: all 4 layers of weights + bias (negated scales) ----
    unsigned int w01[8];    // layer-0 input rows: 2 bf16 packed (q==0 lanes use)
    bf16x8 ain[3][8];       // input A-frags, layers 1..3
    bf16x8 arc[4][8];       // recurrent A-frags, layers 0..3
    f32x4  cbq[4][8];       // bias C quads
#pragma unroll
    for (int g = 0; g < 8; ++g) {
        const int   u_m  = 8 * (m >> 2) + 2 * (g & 3) + (m & 1);
        const int   gt_m = 2 * (g >> 2) + ((m >> 1) & 1);
        const int   rowG = gt_m * 32 + u_m;
        const float sc   = (gt_m == 2) ? NTWOLOG2E : NLOG2E;
        w01[g] = (unsigned int)f2b(Wih0[rowG * 2] * sc)
               | ((unsigned int)f2b(Wih0[rowG * 2 + 1] * sc) << 16);
#pragma unroll
        for (int l = 0; l < 3; ++l) {
            const float* src = Wih + l * 4096 + rowG * 32 + q * 8;
            bf16x8 fr;
#pragma unroll
            for (int jj = 0; jj < 8; ++jj) fr[jj] = (short)f2b(src[jj] * sc);
            ain[l][g] = fr;
        }
#pragma unroll
        for (int l = 0; l < 4; ++l) {
            const float* src = Whh + l * 4096 + rowG * 32 + q * 8;
            bf16x8 fr;
#pragma unroll
            for (int jj = 0; jj < 8; ++jj) fr[jj] = (short)f2b(src[jj] * sc);
            arc[l][g] = fr;
        }
#pragma unroll
        for (int l = 0; l < 4; ++l) {
            f32x4 c4;
#pragma unroll
            for (int r = 0; r < 4; ++r) {
                const int   u_r  = 8 * q + 2 * (g & 3) + (r & 1);
                const int   gt_r = 2 * (g >> 2) + ((r >> 1) & 1);
                const float scr  = (gt_r == 2) ? NTWOLOG2E : NLOG2E;
                c4[r] = (bih[l * 128 + gt_r * 32 + u_r] + bhh[l * 128 + gt_r * 32 + u_r]) * scr;
            }
            cbq[l][g] = c4;
        }
    }

    // persistent register state
    bf16x8 h[4];        // h_l as B-frag; zero = h(0)=0
#pragma unroll
    for (int l = 0; l < 4; ++l) {
        union { unsigned int u[4]; bf16x8 v; } z;
        z.u[0] = 0u; z.u[1] = 0u; z.u[2] = 0u; z.u[3] = 0u;
        h[l] = z.v;
    }
    f32x2 cp[4][4];     // -2log2e*c for unit pair (8q+2j, +1): [l][j]
#pragma unroll
    for (int l = 0; l < 4; ++l)
#pragma unroll
        for (int j = 0; j < 4; ++j) cp[l][j] = (f32x2){0.0f, 0.0f};

    __syncthreads();

    const f32x2 one = {1.0f, 1.0f};
    const f32x2 c2l = {TWOLOG2E, TWOLOG2E};
    const f32x2 n2l = {NTWOLOG2E, NTWOLOG2E};

    // per-layer cell epilogue: acc (4 gates x 8 units) -> h (B-frag) + cp
    auto cell = [&](f32x4 (&acc)[8], bf16x8& hslot, f32x2 (&cps)[4]) {
        union { unsigned int u[4]; bf16x8 v; } hn;
#pragma unroll
        for (int j = 0; j < 4; ++j) {
            f32x2 ai = (f32x2)__builtin_shufflevector(acc[j],     acc[j],     0, 1);
            f32x2 af = (f32x2)__builtin_shufflevector(acc[j],     acc[j],     2, 3);
            f32x2 ag = (f32x2)__builtin_shufflevector(acc[4 + j], acc[4 + j], 0, 1);
            f32x2 ao = (f32x2)__builtin_shufflevector(acc[4 + j], acc[4 + j], 2, 3);
            f32x2 ei = {fex2(ai.x), fex2(ai.y)};              // e^{-a_i}
            f32x2 ef = {fex2(af.x), fex2(af.y)};              // e^{-a_f}
            f32x2 eg = {fex2(ag.x), fex2(ag.y)};              // e^{-2 a_g}
            f32x2 eo = {fex2(ao.x), fex2(ao.y)};              // e^{-a_o}
            f32x2 apf = one + ef;
            f32x2 p1  = (one + ei) * (one + eg);
            f32x2 Dc  = p1 * apf;
            f32x2 R_  = {frcp(Dc.x), frcp(Dc.y)};
            f32x2 egp = __builtin_elementwise_fma(eg, c2l, n2l);  // -2log2e*(1-eg)
            f32x2 t2  = __builtin_elementwise_fma(cps[j], p1, egp * apf);
            f32x2 cn  = t2 * R_;                              // scaled cell state
            cps[j] = cn;
            f32x2 ec  = {fex2(cn.x), fex2(cn.y)};             // e^{-2c}
            f32x2 Dh  = (one + eo) * (one + ec);
            f32x2 Rh  = {frcp(Dh.x), frcp(Dh.y)};
            f32x2 hh  = (one - ec) * Rh;
            hn.u[j] = pk2(hh.x, hh.y);
        }
        hslot = hn.v;
    };

#pragma unroll 1
    for (int t = 0; t < 64; ++t) {
        // ---- layer 0: input = x (K=2) ----
        {
            unsigned int xd = xb[t * 64 + wv * 16 + m];
            union { unsigned int u[4]; bf16x8 v; } bu;
            bu.u[0] = (q == 0) ? xd : 0u; bu.u[1] = 0u; bu.u[2] = 0u; bu.u[3] = 0u;
            f32x4 acc[8];
#pragma unroll
            for (int g = 0; g < 8; ++g) {
                union { unsigned int u[4]; bf16x8 v; } au;
                au.u[0] = (q == 0) ? w01[g] : 0u; au.u[1] = 0u; au.u[2] = 0u; au.u[3] = 0u;
                acc[g] = __builtin_amdgcn_mfma_f32_16x16x32_bf16(au.v, bu.v, cbq[0][g], 0, 0, 0);
                acc[g] = __builtin_amdgcn_mfma_f32_16x16x32_bf16(arc[0][g], h[0], acc[g], 0, 0, 0);
            }
            cell(acc, h[0], cp[0]);
        }
        // ---- layers 1..3: input = h_{l-1}(t) just computed (register) ----
#pragma unroll
        for (int l = 1; l < 4; ++l) {
            f32x4 acc[8];
#pragma unroll
            for (int g = 0; g < 8; ++g) {
                acc[g] = __builtin_amdgcn_mfma_f32_16x16x32_bf16(ain[l - 1][g], h[l - 1], cbq[l][g], 0, 0, 0);
                acc[g] = __builtin_amdgcn_mfma_f32_16x16x32_bf16(arc[l][g], h[l], acc[g], 0, 0, 0);
            }
            cell(acc, h[l], cp[l]);
        }
    }

    // ---- output head: h3(t=63) in registers; reduce across q via shfl ----
    {
        union { unsigned int u[4]; bf16x8 v; } h3; h3.v = h[3];
        float s = 0.0f;
#pragma unroll
        for (int j = 0; j < 4; ++j) {
            unsigned int w2 = h3.u[j];
            const int u0 = 8 * q + 2 * j;
            s += Wlin[u0]     * b2f((unsigned short)(w2 & 0xffffu));
            s += Wlin[u0 + 1] * b2f((unsigned short)(w2 >> 16));
        }
        s += __shfl_xor(s, 16, 64);
        s += __shfl_xor(s, 32, 64);
        if (lane < 16)
            out[row0 + wv * 16 + m] = frcp(1.0f + fex2((s + blin[0]) * NLOG2E));
    }
}

extern "C" void kernel_launch(void* const* d_in, const int* in_sizes, int n_in,
                              void* d_out, int out_size, void* d_ws, size_t ws_size,
                              hipStream_t stream) {
    const float* x    = (const float*)d_in[0];
    const float* Wih0 = (const float*)d_in[1];
    const float* Wih  = (const float*)d_in[2];
    const float* Whh  = (const float*)d_in[3];
    const float* bih  = (const float*)d_in[4];
    const float* bhh  = (const float*)d_in[5];
    const float* Wlin = (const float*)d_in[6];
    const float* blin = (const float*)d_in[7];
    float* out = (float*)d_out;

    lstm_mfma<<<256, 256, 0, stream>>>(x, Wih0, Wih, Whh, bih, bhh, Wlin, blin, out);
}

// Round 9
// 233.366 us; speedup vs baseline: 1.0926x; 1.0926x over previous
//
#include <hip/hip_runtime.h>

typedef float  f32x4  __attribute__((ext_vector_type(4)));
typedef float  f32x2  __attribute__((ext_vector_type(2)));
typedef short  bf16x8 __attribute__((ext_vector_type(8)));

#define TWOLOG2E   2.8853900817779268f
#define NLOG2E    -1.4426950408889634f
#define NTWOLOG2E -2.8853900817779268f

__device__ __forceinline__ unsigned short f2b(float f) {      // fp32 -> bf16 RNE
    unsigned int u = __builtin_bit_cast(unsigned int, f);
    u += 0x7fffu + ((u >> 16) & 1u);
    return (unsigned short)(u >> 16);
}
__device__ __forceinline__ float b2f(unsigned short s) {
    unsigned int u = ((unsigned int)s) << 16;
    return __builtin_bit_cast(float, u);
}
__device__ __forceinline__ unsigned int pk2(float lo, float hi) {
#if __has_builtin(__builtin_amdgcn_cvt_pk_bf16_f32)
    typedef __bf16 bf16x2 __attribute__((ext_vector_type(2)));
    bf16x2 p = __builtin_amdgcn_cvt_pk_bf16_f32(lo, hi);
    return __builtin_bit_cast(unsigned int, p);
#else
    return (unsigned int)f2b(lo) | ((unsigned int)f2b(hi) << 16);
#endif
}
__device__ __forceinline__ float frcp(float x) { return __builtin_amdgcn_rcpf(x); }
__device__ __forceinline__ float fex2(float x) { return __builtin_amdgcn_exp2f(x); }

// R22: 4-waves/SIMD via input-weights-in-LDS. Register map from R15/R19/R21:
// weight-stationary wave = ~165 unified regs -> max 3.1 waves/SIMD; waves are
// ADDITIVE in issue density (1 wave 30%, 2 waves 58%) so occupancy is the
// remaining lever and registers are the only wall. Evict the input-path
// A-frags (32 regs) to LDS (re-read 8x ds_read_b128/cell, linear lane*16B =
// conflict-free, LGKM pipe is idle) and j-interleave MFMA->epilogue so only
// 2 acc quads are live (not 8): ~115 regs < 128 cap => launch_bounds(256,4).
// Geometry: 16 rows/block, grid 1024 = exactly 4 blocks/CU = 4 waves/SIMD.
// LDS 38KB: wlds 24KB (input frags l=1..3) + w0lds 2KB (layer-0 K=2 packed)
// + hb 12KB (handoff slots, layers 0-2 only; wave 3 keeps h3 in regs and
// computes the output head itself). x read direct from global by wave 0
// (predicated q==0, 2 loads/t — latency hidden by 4-wave TLP). No xb.
// Carries R18: gates^T = W·h^T (W=A, h=B); RowMap(g,w): unit=8*(w>>2)+
// 2*(g&3)+(w&1), gate=2*(g>>2)+((w>>1)&1); epilogue pk2 words ARE the next
// B-frag (register recurrence t->t+1); cross-layer = linear ds_*_b128;
// bias in MFMA C (cbq); weights pre-scaled -log2e (-2log2e g-gate).
// Pipeline: wave l = layer l, 2-t supersteps, 35 barriers (R18 schedule).
// Per-unit epilogue (floor: 5 exp2 + 2 rcp, packed f32x2):
//   p1=(1+ei)(1+eg); cn' = [cp*p1 - 2log2e(1-eg)(1+ef)] * rcp(p1*(1+ef))
//   (cp = -2log2e*c);  ec = exp2(cp);  h = (1-ec)*rcp((1+eo)(1+ec))
// HEALTH: WRITE_SIZE ~64KB & VGPR <=128 = fit; WRITE in MBs = spill (R15/R21
// mode) -> revert. Prediction: Occ ~33%, VALUBusy 75-90%, dur ~110-130us.
__global__ __launch_bounds__(256, 4)
void lstm_mfma(const float* __restrict__ xg,  const float* __restrict__ Wih0,
               const float* __restrict__ Wih, const float* __restrict__ Whh,
               const float* __restrict__ bih, const float* __restrict__ bhh,
               const float* __restrict__ Wlin,const float* __restrict__ blin,
               float* __restrict__ out) {
    __shared__ unsigned int wlds[3 * 8 * 64 * 4] __attribute__((aligned(16))); // [l-1][g][lane] 16B frag
    __shared__ unsigned int w0lds[8 * 64];                                     // [g][lane] layer-0 packed (q==0 only)
    __shared__ unsigned int hb[12 * 256] __attribute__((aligned(16)));         // [slot][lane*4+w], slot=(l*2+p)*2+s, l<3

    const int tid  = threadIdx.x;
    const int wv   = __builtin_amdgcn_readfirstlane(tid >> 6);  // layer id, uniform
    const int lane = tid & 63;
    const int m    = lane & 15;    // batch index within 16-row tile
    const int q    = lane >> 4;    // quad: unit octet 8q..8q+7, k-chunk q*8..
    const int row0 = blockIdx.x * 16;

    // ---- cooperative stage: input-weight A-frags (layers 1..3) into LDS ----
    // frag idx: l1 = idx/512 (layer l1+1), g = (idx>>6)&7, ln = idx&63
    for (int idx = tid; idx < 1536; idx += 256) {
        const int l1 = idx >> 9, g = (idx >> 6) & 7, ln = idx & 63;
        const int mm = ln & 15, qq = ln >> 4;
        const int   u_m  = 8 * (mm >> 2) + 2 * (g & 3) + (mm & 1);
        const int   gt_m = 2 * (g >> 2) + ((mm >> 1) & 1);
        const int   rowG = gt_m * 32 + u_m;
        const float sc   = (gt_m == 2) ? NTWOLOG2E : NLOG2E;
        const float* src = Wih + l1 * 4096 + rowG * 32 + qq * 8;
        unsigned int* dst = wlds + idx * 4;
#pragma unroll
        for (int w2 = 0; w2 < 4; ++w2)
            dst[w2] = pk2(src[2 * w2] * sc, src[2 * w2 + 1] * sc);
    }
    // layer-0 input rows: K=2 packed word per (g, lane); nonzero only q==0
    for (int idx = tid; idx < 512; idx += 256) {
        const int g = idx >> 6, ln = idx & 63;
        const int mm = ln & 15, qq = ln >> 4;
        const int   u_m  = 8 * (mm >> 2) + 2 * (g & 3) + (mm & 1);
        const int   gt_m = 2 * (g >> 2) + ((mm >> 1) & 1);
        const int   rowG = gt_m * 32 + u_m;
        const float sc   = (gt_m == 2) ? NTWOLOG2E : NLOG2E;
        w0lds[idx] = (qq == 0) ? pk2(Wih0[rowG * 2] * sc, Wih0[rowG * 2 + 1] * sc) : 0u;
    }

    // ---- per-wave registers: recurrent A-frags + bias quads (own layer) ----
    bf16x8 afr1[8];     // Whh frags: 32 regs
    f32x4  cbq[8];      // bias C quads: 32 regs
#pragma unroll
    for (int g = 0; g < 8; ++g) {
        const int   u_m  = 8 * (m >> 2) + 2 * (g & 3) + (m & 1);
        const int   gt_m = 2 * (g >> 2) + ((m >> 1) & 1);
        const int   rowG = gt_m * 32 + u_m;
        const float sc   = (gt_m == 2) ? NTWOLOG2E : NLOG2E;
        const float* src = Whh + wv * 4096 + rowG * 32 + q * 8;
        bf16x8 fr;
#pragma unroll
        for (int jj = 0; jj < 8; ++jj) fr[jj] = (short)f2b(src[jj] * sc);
        afr1[g] = fr;
        f32x4 c4;
#pragma unroll
        for (int r = 0; r < 4; ++r) {
            const int   u_r  = 8 * q + 2 * (g & 3) + (r & 1);
            const int   gt_r = 2 * (g >> 2) + ((r >> 1) & 1);
            const float scr  = (gt_r == 2) ? NTWOLOG2E : NLOG2E;
            c4[r] = (bih[wv * 128 + gt_r * 32 + u_r] + bhh[wv * 128 + gt_r * 32 + u_r]) * scr;
        }
        cbq[g] = c4;
    }

    // persistent state
    bf16x8 hreg;        // h as next-B-frag; zero init
    {
        union { unsigned int u[4]; bf16x8 v; } z;
        z.u[0] = 0u; z.u[1] = 0u; z.u[2] = 0u; z.u[3] = 0u;
        hreg = z.v;
    }
    f32x2 cp2[4];       // -2log2e*c for unit pair (8q+2j, +1)
#pragma unroll
    for (int j = 0; j < 4; ++j) cp2[j] = (f32x2){0.0f, 0.0f};

    __syncthreads();

    const f32x2 one = {1.0f, 1.0f};
    const f32x2 c2l = {TWOLOG2E, TWOLOG2E};
    const f32x2 n2l = {NTWOLOG2E, NTWOLOG2E};

    // one timestep for this wave's 16 rows; j-interleaved MFMA->epilogue
    // keeps only 2 acc quads live.
    auto cell_step = [&](int t, int sidx_in, int sidx_out) {
        // input B-frag
        bf16x8 bin;
        if (wv == 0) {
            union { unsigned int u[4]; bf16x8 v; } bu;
            bu.u[0] = 0u; bu.u[1] = 0u; bu.u[2] = 0u; bu.u[3] = 0u;
            if (q == 0) {
                float x0 = xg[(size_t)(row0 + m) * 192 + t];
                float x1 = xg[(size_t)(row0 + m) * 192 + 64 + t];
                bu.u[0] = pk2(x0, x1);
            }
            bin = bu.v;
        } else {
            bin = *(const bf16x8*)(hb + sidx_in * 256 + lane * 4);
        }

        union { unsigned int u[4]; bf16x8 v; } hn;
#pragma unroll
        for (int j = 0; j < 4; ++j) {
            f32x4 accA, accB;
            if (wv == 0) {
                union { unsigned int u[4]; bf16x8 v; } au, av;
                au.u[0] = w0lds[j * 64 + lane];       au.u[1] = 0u; au.u[2] = 0u; au.u[3] = 0u;
                av.u[0] = w0lds[(4 + j) * 64 + lane]; av.u[1] = 0u; av.u[2] = 0u; av.u[3] = 0u;
                accA = __builtin_amdgcn_mfma_f32_16x16x32_bf16(au.v, bin, cbq[j],     0, 0, 0);
                accB = __builtin_amdgcn_mfma_f32_16x16x32_bf16(av.v, bin, cbq[4 + j], 0, 0, 0);
            } else {
                const bf16x8 fa = *(const bf16x8*)(wlds + (((wv - 1) * 8 + j)     * 64 + lane) * 4);
                const bf16x8 fb = *(const bf16x8*)(wlds + (((wv - 1) * 8 + 4 + j) * 64 + lane) * 4);
                accA = __builtin_amdgcn_mfma_f32_16x16x32_bf16(fa, bin, cbq[j],     0, 0, 0);
                accB = __builtin_amdgcn_mfma_f32_16x16x32_bf16(fb, bin, cbq[4 + j], 0, 0, 0);
            }
            accA = __builtin_amdgcn_mfma_f32_16x16x32_bf16(afr1[j],     hreg, accA, 0, 0, 0);
            accB = __builtin_amdgcn_mfma_f32_16x16x32_bf16(afr1[4 + j], hreg, accB, 0, 0, 0);

            // epilogue for unit pair (8q+2j, 8q+2j+1)
            f32x2 ai = (f32x2)__builtin_shufflevector(accA, accA, 0, 1);
            f32x2 af = (f32x2)__builtin_shufflevector(accA, accA, 2, 3);
            f32x2 ag = (f32x2)__builtin_shufflevector(accB, accB, 0, 1);
            f32x2 ao = (f32x2)__builtin_shufflevector(accB, accB, 2, 3);
            f32x2 ei = {fex2(ai.x), fex2(ai.y)};              // e^{-a_i}
            f32x2 ef = {fex2(af.x), fex2(af.y)};              // e^{-a_f}
            f32x2 eg = {fex2(ag.x), fex2(ag.y)};              // e^{-2 a_g}
            f32x2 eo = {fex2(ao.x), fex2(ao.y)};              // e^{-a_o}
            f32x2 apf = one + ef;
            f32x2 p1  = (one + ei) * (one + eg);
            f32x2 Dc  = p1 * apf;
            f32x2 R_  = {frcp(Dc.x), frcp(Dc.y)};
            f32x2 egp = __builtin_elementwise_fma(eg, c2l, n2l);  // -2log2e*(1-eg)
            f32x2 t2  = __builtin_elementwise_fma(cp2[j], p1, egp * apf);
            f32x2 cn  = t2 * R_;                              // scaled cell state
            cp2[j] = cn;
            f32x2 ec  = {fex2(cn.x), fex2(cn.y)};             // e^{-2c}
            f32x2 Dh  = (one + eo) * (one + ec);
            f32x2 Rh  = {frcp(Dh.x), frcp(Dh.y)};
            f32x2 hh  = (one - ec) * Rh;
            hn.u[j] = pk2(hh.x, hh.y);
        }
        hreg = hn.v;                                           // register recurrence
        if (sidx_out >= 0)
            *(bf16x8*)(hb + sidx_out * 256 + lane * 4) = hn.v; // cross-layer handoff
    };

    for (int S = 0; S < 35; ++S) {
        const int t0 = 2 * (S - wv);          // wave-uniform
        if (t0 >= 0 && t0 <= 62) {
            const int p  = S & 1;
            const int pb = p ^ 1;
            const int si = (wv > 0) ? (((wv - 1) * 2 + pb) * 2) : -1;   // input slots (s=0,1)
            const int so = (wv < 3) ? ((wv * 2 + p) * 2)        : -1;   // output slots
            cell_step(t0,     si,              so);
            cell_step(t0 + 1, si < 0 ? -1 : si + 1, so < 0 ? -1 : so + 1);
        }
        __syncthreads();
    }

    // ---- output head: wave 3 holds h3(t=63) in hreg ----
    if (wv == 3) {
        union { unsigned int u[4]; bf16x8 v; } h3; h3.v = hreg;
        float s = 0.0f;
#pragma unroll
        for (int j = 0; j < 4; ++j) {
            unsigned int w2 = h3.u[j];
            const int u0 = 8 * q + 2 * j;
            s += Wlin[u0]     * b2f((unsigned short)(w2 & 0xffffu));
            s += Wlin[u0 + 1] * b2f((unsigned short)(w2 >> 16));
        }
        s += __shfl_xor(s, 16, 64);
        s += __shfl_xor(s, 32, 64);
        if (lane < 16)
            out[row0 + m] = frcp(1.0f + fex2((s + blin[0]) * NLOG2E));
    }
}

extern "C" void kernel_launch(void* const* d_in, const int* in_sizes, int n_in,
                              void* d_out, int out_size, void* d_ws, size_t ws_size,
                              hipStream_t stream) {
    const float* x    = (const float*)d_in[0];
    const float* Wih0 = (const float*)d_in[1];
    const float* Wih  = (const float*)d_in[2];
    const float* Whh  = (const float*)d_in[3];
    const float* bih  = (const float*)d_in[4];
    const float* bhh  = (const float*)d_in[5];
    const float* Wlin = (const float*)d_in[6];
    const float* blin = (const float*)d_in[7];
    float* out = (float*)d_out;

    lstm_mfma<<<1024, 256, 0, stream>>>(x, Wih0, Wih, Whh, bih, bhh, Wlin, blin, out);
}

// Round 10
// 222.142 us; speedup vs baseline: 1.1478x; 1.0505x over previous
//
#include <hip/hip_runtime.h>

typedef float  f32x4  __attribute__((ext_vector_type(4)));
typedef float  f32x2  __attribute__((ext_vector_type(2)));
typedef short  bf16x8 __attribute__((ext_vector_type(8)));

#define TWOLOG2E   2.8853900817779268f
#define NLOG2E    -1.4426950408889634f
#define NTWOLOG2E -2.8853900817779268f

__device__ __forceinline__ unsigned short f2b(float f) {      // fp32 -> bf16 RNE
    unsigned int u = __builtin_bit_cast(unsigned int, f);
    u += 0x7fffu + ((u >> 16) & 1u);
    return (unsigned short)(u >> 16);
}
__device__ __forceinline__ float b2f(unsigned short s) {
    unsigned int u = ((unsigned int)s) << 16;
    return __builtin_bit_cast(float, u);
}
__device__ __forceinline__ unsigned int pk2(float lo, float hi) {
#if __has_builtin(__builtin_amdgcn_cvt_pk_bf16_f32)
    typedef __bf16 bf16x2 __attribute__((ext_vector_type(2)));
    bf16x2 p = __builtin_amdgcn_cvt_pk_bf16_f32(lo, hi);
    return __builtin_bit_cast(unsigned int, p);
#else
    return (unsigned int)f2b(lo) | ((unsigned int)f2b(hi) << 16);
#endif
}
__device__ __forceinline__ float frcp(float x) { return __builtin_amdgcn_rcpf(x); }
__device__ __forceinline__ float fex2(float x) { return __builtin_amdgcn_exp2f(x); }

// R23: trans-count reduction on the R17 base (best family: R14/R17 = 165.1/
// 165.7us). R14-R22 mapped the structure space completely — 2 waves/SIMD x
// 32 rows is the fixed point; VALUBusy*dur ~= 96us invariant, trans-dominated.
// This round removes trans instructions instead of rescheduling them: the two
// scalar v_rcp per packed chain fuse pairwise via 1/a = b*rcp(ab), 1/b =
// a*rcp(ab) — applied to both R_ (cell denom) and Rh (output denom). Trans
// per unit: 5 exp + 2 rcp -> 5 exp + 1 rcp (7 -> 6, -14% trans mass, net
// ~-96cyc/cell_step after the 3-mul tax per fused pair).
// Overflow audit: Dc <= ~8e13 (preacts bounded ~±8) -> product 6e27 OK.
// Dh contains ec = 2^cn, cn unbounded by c-accumulation -> clamp the EXP
// INPUT only at 50 (ec <= 1.1e15, product <= 2.6e34 OK; h error at the clamp
// ~1e-15; the unclamped kernel itself NaNs at cn>128 so this is strictly
// safer). cp recurrence stores UNCLAMPED cn. Paired rcp adds ~2ulp to R_/Rh
// (~1e-7 rel on h; 4 orders below bf16 rounding).
// Base structure (R17): 32 rows/block, grid 512, 2 blocks/CU = 2 waves/SIMD,
// wave l owns layer l, 2-timestep supersteps, 35 barriers, bias in MFMA C
// (cbq), B-frags pre-scaled -log2e (-2log2e g-gate), row-axis f32x2 pairing
// (sub-register slices of MFMA dst quads, zero movs). Epilogue math:
//   p1=(1+ei)(1+eg); cn' = [cp*p1 - 2log2e(1-eg)(1+ef)] * rcp(p1*(1+ef))
//   (cp = -2log2e*c);  ec = exp2(min(cn,50));  h = (1-ec)*rcp((1+eo)(1+ec))
// History: R15/R22 occupancy (spill/overhead), R16/R19 manual overlap (AGPR
// tax), R17/R20 pairing/SoA (neutral), R18 reg-recurrence (neutral), R21
// monolith (spill). All structural levers exhausted; this is the math lever.
__global__ __launch_bounds__(256, 2)
void lstm_mfma(const float* __restrict__ xg,  const float* __restrict__ Wih0,
               const float* __restrict__ Wih, const float* __restrict__ Whh,
               const float* __restrict__ bih, const float* __restrict__ bhh,
               const float* __restrict__ Wlin,const float* __restrict__ blin,
               float* __restrict__ out) {
    __shared__ short        hb[16 * 1280] __attribute__((aligned(16))); // [l][p][slot][32row*40]
    __shared__ unsigned int xb[64 * 32];                                // [t][row] 2xbf16

    const int tid  = threadIdx.x;
    const int wv   = __builtin_amdgcn_readfirstlane(tid >> 6);  // layer id, uniform
    const int lane = tid & 63;
    const int m    = lane & 15;    // A-row / D-col index
    const int q    = lane >> 4;    // quad
    const int row0 = blockIdx.x * 32;

    // zero all h buffers (first reads must see 0)
    for (int i = tid; i < 10240; i += 256) ((unsigned int*)hb)[i] = 0u;

    // stage x -> LDS bf16 [t][row]
    for (int i = tid; i < 2048; i += 256) {
        int r = i >> 6, t = i & 63;
        float x0 = xg[(size_t)(row0 + r) * 192 + t];
        float x1 = xg[(size_t)(row0 + r) * 192 + 64 + t];
        xb[t * 32 + r] = pk2(x0, x1);
    }

    // ---- one-time gather of B-frags + bias (negated scales) ----
    // tile g: gate T=g>>1 of unit 2m+(g&1); rowG = T*32 + 2m + (g&1).
    bf16x8 bfr[8][2];
    float  bv[8];
#pragma unroll
    for (int g = 0; g < 8; ++g) {
        const int   T    = g >> 1;
        const int   rowG = T * 32 + 2 * m + (g & 1);
        const float sc   = (T == 2) ? NTWOLOG2E : NLOG2E;
        bv[g] = (bih[wv * 128 + rowG] + bhh[wv * 128 + rowG]) * sc;
#pragma unroll
        for (int c = 0; c < 2; ++c) {
            const int k0 = c * 32 + q * 8;
            float w[8];
            if (wv == 0) {
                if (c == 0) {
#pragma unroll
                    for (int jj = 0; jj < 8; ++jj) w[jj] = 0.0f;
                    if (q == 0) { w[0] = Wih0[rowG * 2]; w[1] = Wih0[rowG * 2 + 1]; }
                } else {
                    const float* src = Whh + rowG * 32 + (k0 - 32);
#pragma unroll
                    for (int jj = 0; jj < 8; ++jj) w[jj] = src[jj];
                }
            } else {
                const float* src = (c == 0) ? (Wih + (wv - 1) * 4096 + rowG * 32 + k0)
                                            : (Whh + wv * 4096 + rowG * 32 + (k0 - 32));
#pragma unroll
                for (int jj = 0; jj < 8; ++jj) w[jj] = src[jj];
            }
            bf16x8 fr;
#pragma unroll
            for (int jj = 0; jj < 8; ++jj) fr[jj] = (short)f2b(w[jj] * sc);
            bfr[g][c] = fr;
        }
    }

    // hoisted bias C-operand quads (persistent; bias rides into MFMA)
    f32x4 cbq[8];
#pragma unroll
    for (int g = 0; g < 8; ++g) {
        f32x4 c4 = {bv[g], bv[g], bv[g], bv[g]};
        cbq[g] = c4;
    }

    // scaled cell state -2log2e*c: [tt][hf][rp], f32x2 over row-pair (2rp,2rp+1)
    f32x2 cp2[2][2][2];
#pragma unroll
    for (int tt = 0; tt < 2; ++tt)
#pragma unroll
        for (int hf = 0; hf < 2; ++hf)
#pragma unroll
            for (int rp = 0; rp < 2; ++rp) cp2[tt][hf][rp] = (f32x2){0.0f, 0.0f};

    // hoisted per-lane LDS offsets
    const int aoff = m * 40 + q * 8;        // short-index A-frag offset within slot
    const int woff = q * 80 + m;            // uint-index h-write offset within slot

    __syncthreads();

    // packed LSTM epilogue chain over a row-pair for one unit column.
    // PAIRED RCP: the two scalar rcps of each f32x2 denominator fuse into one:
    //   r = rcp(D.x*D.y); 1/D.x = D.y*r; 1/D.y = D.x*r.
    auto chain = [&](f32x2 ai, f32x2 af, f32x2 ag, f32x2 ao, f32x2& cpr) -> f32x2 {
        const f32x2 one = {1.0f, 1.0f};
        const f32x2 c2l = {TWOLOG2E, TWOLOG2E};
        const f32x2 n2l = {NTWOLOG2E, NTWOLOG2E};
        f32x2 ei = {fex2(ai.x), fex2(ai.y)};              // e^{-a_i}
        f32x2 ef = {fex2(af.x), fex2(af.y)};              // e^{-a_f}
        f32x2 eg = {fex2(ag.x), fex2(ag.y)};              // e^{-2 a_g}
        f32x2 eo = {fex2(ao.x), fex2(ao.y)};              // e^{-a_o}
        f32x2 apf = one + ef;
        f32x2 p1  = (one + ei) * (one + eg);
        f32x2 Dc  = p1 * apf;                             // <= ~8e13; product safe
        float rC  = frcp(Dc.x * Dc.y);
        f32x2 R_  = {Dc.y * rC, Dc.x * rC};
        f32x2 egp = __builtin_elementwise_fma(eg, c2l, n2l);  // -2log2e*(1-eg)
        f32x2 t1  = egp * apf;
        f32x2 t2  = __builtin_elementwise_fma(cpr, p1, t1);
        f32x2 cn  = t2 * R_;                              // scaled cell state
        cpr = cn;                                         // recurrence: UNCLAMPED
        f32x2 cne = __builtin_elementwise_min(cn, (f32x2){50.0f, 50.0f});
        f32x2 ec  = {fex2(cne.x), fex2(cne.y)};           // e^{-2c}, <= 1.1e15
        f32x2 Dh  = (one + eo) * (one + ec);              // product <= 2.6e34
        float rH  = frcp(Dh.x * Dh.y);
        f32x2 Rh  = {Dh.y * rH, Dh.x * rH};
        return (one - ec) * Rh;
    };

    // one t cell-step for all 32 rows (2 row-tiles)
    auto cell_step = [&](int t, const short* pa0, const short* pa1, short* hwr) {
        bf16x8 a0[2], a1[2];
#pragma unroll
        for (int tt = 0; tt < 2; ++tt) {
            if (wv == 0) {
                unsigned int xd = xb[t * 32 + tt * 16 + m];
                union { unsigned int u[4]; bf16x8 v; } au;
                au.u[0] = (q == 0) ? xd : 0u; au.u[1] = 0u; au.u[2] = 0u; au.u[3] = 0u;
                a0[tt] = au.v;
            } else {
                a0[tt] = *(const bf16x8*)(pa0 + aoff + tt * 640);
            }
            a1[tt] = *(const bf16x8*)(pa1 + aoff + tt * 640);
        }
#pragma unroll
        for (int tt = 0; tt < 2; ++tt) {
            f32x4 acc[8];
#pragma unroll
            for (int g = 0; g < 8; ++g) {
                acc[g] = __builtin_amdgcn_mfma_f32_16x16x32_bf16(a0[tt], bfr[g][0], cbq[g], 0, 0, 0);
                acc[g] = __builtin_amdgcn_mfma_f32_16x16x32_bf16(a1[tt], bfr[g][1], acc[g], 0, 0, 0);
            }
#pragma unroll
            for (int rp = 0; rp < 2; ++rp) {
                // sub-register f32x2 slices of the MFMA dst quads (no movs)
                f32x2 ai0 = rp ? (f32x2)__builtin_shufflevector(acc[0], acc[0], 2, 3)
                               : (f32x2)__builtin_shufflevector(acc[0], acc[0], 0, 1);
                f32x2 ai1 = rp ? (f32x2)__builtin_shufflevector(acc[1], acc[1], 2, 3)
                               : (f32x2)__builtin_shufflevector(acc[1], acc[1], 0, 1);
                f32x2 af0 = rp ? (f32x2)__builtin_shufflevector(acc[2], acc[2], 2, 3)
                               : (f32x2)__builtin_shufflevector(acc[2], acc[2], 0, 1);
                f32x2 af1 = rp ? (f32x2)__builtin_shufflevector(acc[3], acc[3], 2, 3)
                               : (f32x2)__builtin_shufflevector(acc[3], acc[3], 0, 1);
                f32x2 ag0 = rp ? (f32x2)__builtin_shufflevector(acc[4], acc[4], 2, 3)
                               : (f32x2)__builtin_shufflevector(acc[4], acc[4], 0, 1);
                f32x2 ag1 = rp ? (f32x2)__builtin_shufflevector(acc[5], acc[5], 2, 3)
                               : (f32x2)__builtin_shufflevector(acc[5], acc[5], 0, 1);
                f32x2 ao0 = rp ? (f32x2)__builtin_shufflevector(acc[6], acc[6], 2, 3)
                               : (f32x2)__builtin_shufflevector(acc[6], acc[6], 0, 1);
                f32x2 ao1 = rp ? (f32x2)__builtin_shufflevector(acc[7], acc[7], 2, 3)
                               : (f32x2)__builtin_shufflevector(acc[7], acc[7], 0, 1);

                f32x2 hh0 = chain(ai0, af0, ag0, ao0, cp2[tt][0][rp]);   // unit 2m
                f32x2 hh1 = chain(ai1, af1, ag1, ao1, cp2[tt][1][rp]);   // unit 2m+1

                ((unsigned int*)hwr)[woff + tt * 320 + (2 * rp    ) * 20] = pk2(hh0.x, hh1.x);
                ((unsigned int*)hwr)[woff + tt * 320 + (2 * rp + 1) * 20] = pk2(hh0.y, hh1.y);
            }
        }
    };

    for (int S = 0; S < 35; ++S) {
        const int t0 = 2 * (S - wv);          // wave-uniform
        if (t0 >= 0 && t0 <= 62) {
            const int p  = S & 1;
            const int pb = p ^ 1;
            short*       Lc0 = hb + ((wv * 2 + p ) * 2    ) * 1280;  // own layer, cur parity, slot0
            short*       Lc1 = Lc0 + 1280;                            // slot1
            const short* Lp1 = hb + ((wv * 2 + pb) * 2 + 1) * 1280;  // own layer, prev parity, slot1
            const int    lb  = (wv > 0) ? (wv - 1) : 0;
            const short* Dp0 = hb + ((lb * 2 + pb) * 2    ) * 1280;  // layer below, prev parity, slot0
            const short* Dp1 = Dp0 + 1280;                            // slot1

            cell_step(t0,     Dp0, Lp1, Lc0);   // t0: input h_{l-1}(t0), recurrent h_l(t0-1)
            cell_step(t0 + 1, Dp1, Lc0, Lc1);   // t1: input h_{l-1}(t1), recurrent h_l(t0)
        }
        __syncthreads();
    }

    // output head: h3(t=63) -> S=34, p=0, slot1
    if (tid < 32) {
        const short* h3 = hb + ((3 * 2 + 0) * 2 + 1) * 1280;
        float s = blin[0];
#pragma unroll
        for (int k = 0; k < 32; ++k)
            s += Wlin[k] * b2f((unsigned short)h3[tid * 40 + k]);
        out[row0 + tid] = frcp(1.0f + fex2(s * NLOG2E));
    }
}

extern "C" void kernel_launch(void* const* d_in, const int* in_sizes, int n_in,
                              void* d_out, int out_size, void* d_ws, size_t ws_size,
                              hipStream_t stream) {
    const float* x    = (const float*)d_in[0];
    const float* Wih0 = (const float*)d_in[1];
    const float* Wih  = (const float*)d_in[2];
    const float* Whh  = (const float*)d_in[3];
    const float* bih  = (const float*)d_in[4];
    const float* bhh  = (const float*)d_in[5];
    const float* Wlin = (const float*)d_in[6];
    const float* blin = (const float*)d_in[7];
    float* out = (float*)d_out;

    lstm_mfma<<<512, 256, 0, stream>>>(x, Wih0, Wih, Whh, bih, bhh, Wlin, blin, out);
}

// Round 12
// 215.308 us; speedup vs baseline: 1.1842x; 1.0317x over previous
//
#include <hip/hip_runtime.h>

typedef float  f32x4  __attribute__((ext_vector_type(4)));
typedef float  f32x2  __attribute__((ext_vector_type(2)));
typedef short  bf16x8 __attribute__((ext_vector_type(8)));

#define TWOLOG2E   2.8853900817779268f
#define NLOG2E    -1.4426950408889634f
#define NTWOLOG2E -2.8853900817779268f

__device__ __forceinline__ unsigned short f2b(float f) {      // fp32 -> bf16 RNE
    unsigned int u = __builtin_bit_cast(unsigned int, f);
    u += 0x7fffu + ((u >> 16) & 1u);
    return (unsigned short)(u >> 16);
}
__device__ __forceinline__ float b2f(unsigned short s) {
    unsigned int u = ((unsigned int)s) << 16;
    return __builtin_bit_cast(float, u);
}
__device__ __forceinline__ unsigned int pk2(float lo, float hi) {
#if __has_builtin(__builtin_amdgcn_cvt_pk_bf16_f32)
    typedef __bf16 bf16x2 __attribute__((ext_vector_type(2)));
    bf16x2 p = __builtin_amdgcn_cvt_pk_bf16_f32(lo, hi);
    return __builtin_bit_cast(unsigned int, p);
#else
    return (unsigned int)f2b(lo) | ((unsigned int)f2b(hi) << 16);
#endif
}
__device__ __forceinline__ float frcp(float x) { return __builtin_amdgcn_rcpf(x); }
__device__ __forceinline__ float fex2(float x) { return __builtin_amdgcn_exp2f(x); }

// FINAL (R14 configuration; resubmitted after R11 infra failure): best
// measured configuration, 165.1us kernel / 215.7us bench, absmax 0.
// Structure: block=256 (4 waves), 32 rows/block, grid 512 = 2 blocks/CU =
// 2 waves/SIMD; wave l owns layer l; B-frags (128 gate-rows x K=64 bf16)
// live in VGPRs pre-scaled by -log2e (-2log2e for g) so MFMA emits NEGATED
// scaled preacts; bias rides in the MFMA C operand (cbq, hoisted);
// 2-timestep supersteps, 35 barriers; h crosses layers via LDS
// [l][parity][slot][32row*40] bf16 A-frag layout. Epilogue: packed f32x2
// over the two hf halves (v_pk_{add,mul,fma}_f32), scalar exp2/rcp per half:
//   p1=(1+ei)(1+eg); cn' = [cp*p1 - 2log2e(1-eg)(1+ef)] * rcp(p1*(1+ef))
//   (cp = -2log2e*c);  ec = exp2(cp);  h = (1-ec)*rcp((1+eo)(1+ec))
// SESSION MAP (all falsified on HW, do not retry without new information):
//   R15/R22 occupancy>2waves: register wall ~165 regs/wave weight-stationary
//     -> spill (WRITE_SIZE MBs) or work-dilution (3rd wave adds 0 issue)
//   R16/R19/R21 manual ILP / monolith: AGPR-move tax or 256-cap spill;
//     compiler already interleaves straight-line independent chains
//   R17/R20/R23 epilogue variants (row-pairing / SoA / paired-rcp): neutral
//     or worse — 5exp+2rcp with independent rcps is the dependency floor
//   R18 register recurrence + conflict-free LDS: neutral (LDS not binding)
// Invariant: VALUBusy*dur ~= 96us across ALL structures; residual ~40% idle
// is serial recurrence latency (ds_read -> 2 chained MFMA -> 3-level trans
// chain) unfillable at 2 waves/SIMD. Latency-bound local minimum.
__global__ __launch_bounds__(256, 2)
void lstm_mfma(const float* __restrict__ xg,  const float* __restrict__ Wih0,
               const float* __restrict__ Wih, const float* __restrict__ Whh,
               const float* __restrict__ bih, const float* __restrict__ bhh,
               const float* __restrict__ Wlin,const float* __restrict__ blin,
               float* __restrict__ out) {
    __shared__ short        hb[16 * 1280] __attribute__((aligned(16))); // [l][p][slot][32row*40]
    __shared__ unsigned int xb[64 * 32];                                // [t][row] 2xbf16

    const int tid  = threadIdx.x;
    const int wv   = __builtin_amdgcn_readfirstlane(tid >> 6);  // layer id, uniform
    const int lane = tid & 63;
    const int m    = lane & 15;    // A-row / D-col index
    const int q    = lane >> 4;    // quad
    const int row0 = blockIdx.x * 32;

    // zero all h buffers (first reads must see 0)
    for (int i = tid; i < 10240; i += 256) ((unsigned int*)hb)[i] = 0u;

    // stage x -> LDS bf16 [t][row]
    for (int i = tid; i < 2048; i += 256) {
        int r = i >> 6, t = i & 63;
        float x0 = xg[(size_t)(row0 + r) * 192 + t];
        float x1 = xg[(size_t)(row0 + r) * 192 + 64 + t];
        xb[t * 32 + r] = pk2(x0, x1);
    }

    // ---- one-time gather of B-frags + bias (negated scales) ----
    // tile g: gate T=g>>1 of unit 2m+(g&1); rowG = T*32 + 2m + (g&1).
    bf16x8 bfr[8][2];
    float  bv[8];
#pragma unroll
    for (int g = 0; g < 8; ++g) {
        const int   T    = g >> 1;
        const int   rowG = T * 32 + 2 * m + (g & 1);
        const float sc   = (T == 2) ? NTWOLOG2E : NLOG2E;
        bv[g] = (bih[wv * 128 + rowG] + bhh[wv * 128 + rowG]) * sc;
#pragma unroll
        for (int c = 0; c < 2; ++c) {
            const int k0 = c * 32 + q * 8;
            float w[8];
            if (wv == 0) {
                if (c == 0) {
#pragma unroll
                    for (int jj = 0; jj < 8; ++jj) w[jj] = 0.0f;
                    if (q == 0) { w[0] = Wih0[rowG * 2]; w[1] = Wih0[rowG * 2 + 1]; }
                } else {
                    const float* src = Whh + rowG * 32 + (k0 - 32);
#pragma unroll
                    for (int jj = 0; jj < 8; ++jj) w[jj] = src[jj];
                }
            } else {
                const float* src = (c == 0) ? (Wih + (wv - 1) * 4096 + rowG * 32 + k0)
                                            : (Whh + wv * 4096 + rowG * 32 + (k0 - 32));
#pragma unroll
                for (int jj = 0; jj < 8; ++jj) w[jj] = src[jj];
            }
            bf16x8 fr;
#pragma unroll
            for (int jj = 0; jj < 8; ++jj) fr[jj] = (short)f2b(w[jj] * sc);
            bfr[g][c] = fr;
        }
    }

    // hoisted bias C-operand quads (persistent; avoids per-MFMA re-splat)
    f32x4 cbq[8];
#pragma unroll
    for (int g = 0; g < 8; ++g) {
        f32x4 c4 = {bv[g], bv[g], bv[g], bv[g]};
        cbq[g] = c4;
    }

    f32x2 cp2[2][4];   // scaled cell state -2log2e*c: [tt][r], .x=hf0 .y=hf1
#pragma unroll
    for (int tt = 0; tt < 2; ++tt)
#pragma unroll
        for (int r = 0; r < 4; ++r) cp2[tt][r] = (f32x2){0.0f, 0.0f};

    // hoisted per-lane LDS offsets
    const int aoff = m * 40 + q * 8;        // short-index A-frag offset within slot
    const int woff = q * 80 + m;            // uint-index h-write offset within slot

    __syncthreads();

    // one t cell-step for all 32 rows (2 row-tiles)
    auto cell_step = [&](int t, const short* pa0, const short* pa1, short* hwr) {
        bf16x8 a0[2], a1[2];
#pragma unroll
        for (int tt = 0; tt < 2; ++tt) {
            if (wv == 0) {
                unsigned int xd = xb[t * 32 + tt * 16 + m];
                union { unsigned int u[4]; bf16x8 v; } au;
                au.u[0] = (q == 0) ? xd : 0u; au.u[1] = 0u; au.u[2] = 0u; au.u[3] = 0u;
                a0[tt] = au.v;
            } else {
                a0[tt] = *(const bf16x8*)(pa0 + aoff + tt * 640);
            }
            a1[tt] = *(const bf16x8*)(pa1 + aoff + tt * 640);
        }
#pragma unroll
        for (int tt = 0; tt < 2; ++tt) {
            f32x4 acc[8];
#pragma unroll
            for (int g = 0; g < 8; ++g) {
                acc[g] = __builtin_amdgcn_mfma_f32_16x16x32_bf16(a0[tt], bfr[g][0], cbq[g], 0, 0, 0);
                acc[g] = __builtin_amdgcn_mfma_f32_16x16x32_bf16(a1[tt], bfr[g][1], acc[g], 0, 0, 0);
            }
            const f32x2 one  = {1.0f, 1.0f};
            const f32x2 c2l  = {TWOLOG2E, TWOLOG2E};
            const f32x2 n2l  = {NTWOLOG2E, NTWOLOG2E};
#pragma unroll
            for (int r = 0; r < 4; ++r) {
                f32x2 ei = {fex2(acc[0][r]), fex2(acc[1][r])};   // e^{-a_i}, both hf halves
                f32x2 ef = {fex2(acc[2][r]), fex2(acc[3][r])};   // e^{-a_f}
                f32x2 eg = {fex2(acc[4][r]), fex2(acc[5][r])};   // e^{-2 a_g}
                f32x2 eo = {fex2(acc[6][r]), fex2(acc[7][r])};   // e^{-a_o}
                f32x2 apf = one + ef;
                f32x2 p1  = (one + ei) * (one + eg);
                f32x2 Dc  = p1 * apf;
                f32x2 R_  = {frcp(Dc.x), frcp(Dc.y)};
                f32x2 egp = __builtin_elementwise_fma(eg, c2l, n2l);  // -2log2e*(1-eg)
                f32x2 t1  = egp * apf;
                f32x2 t2  = __builtin_elementwise_fma(cp2[tt][r], p1, t1);
                f32x2 cn  = t2 * R_;                              // scaled cell state
                cp2[tt][r] = cn;
                f32x2 ec  = {fex2(cn.x), fex2(cn.y)};             // e^{-2c}
                f32x2 Dh  = (one + eo) * (one + ec);
                f32x2 Rh  = {frcp(Dh.x), frcp(Dh.y)};
                f32x2 hh  = (one - ec) * Rh;
                ((unsigned int*)hwr)[woff + tt * 320 + r * 20] = pk2(hh.x, hh.y);
            }
        }
    };

    for (int S = 0; S < 35; ++S) {
        const int t0 = 2 * (S - wv);          // wave-uniform
        if (t0 >= 0 && t0 <= 62) {
            const int p  = S & 1;
            const int pb = p ^ 1;
            short*       Lc0 = hb + ((wv * 2 + p ) * 2    ) * 1280;  // own layer, cur parity, slot0
            short*       Lc1 = Lc0 + 1280;                            // slot1
            const short* Lp1 = hb + ((wv * 2 + pb) * 2 + 1) * 1280;  // own layer, prev parity, slot1
            const int    lb  = (wv > 0) ? (wv - 1) : 0;
            const short* Dp0 = hb + ((lb * 2 + pb) * 2    ) * 1280;  // layer below, prev parity, slot0
            const short* Dp1 = Dp0 + 1280;                            // slot1

            cell_step(t0,     Dp0, Lp1, Lc0);   // t0: input h_{l-1}(t0), recurrent h_l(t0-1)
            cell_step(t0 + 1, Dp1, Lc0, Lc1);   // t1: input h_{l-1}(t1), recurrent h_l(t0)
        }
        __syncthreads();
    }

    // output head: h3(t=63) -> S=34, p=0, slot1
    if (tid < 32) {
        const short* h3 = hb + ((3 * 2 + 0) * 2 + 1) * 1280;
        float s = blin[0];
#pragma unroll
        for (int k = 0; k < 32; ++k)
            s += Wlin[k] * b2f((unsigned short)h3[tid * 40 + k]);
        out[row0 + tid] = frcp(1.0f + fex2(s * NLOG2E));
    }
}

extern "C" void kernel_launch(void* const* d_in, const int* in_sizes, int n_in,
                              void* d_out, int out_size, void* d_ws, size_t ws_size,
                              hipStream_t stream) {
    const float* x    = (const float*)d_in[0];
    const float* Wih0 = (const float*)d_in[1];
    const float* Wih  = (const float*)d_in[2];
    const float* Whh  = (const float*)d_in[3];
    const float* bih  = (const float*)d_in[4];
    const float* bhh  = (const float*)d_in[5];
    const float* Wlin = (const float*)d_in[6];
    const float* blin = (const float*)d_in[7];
    float* out = (float*)d_out;

    lstm_mfma<<<512, 256, 0, stream>>>(x, Wih0, Wih, Whh, bih, bhh, Wlin, blin, out);
}